// Round 5
// baseline (224.435 us; speedup 1.0000x reference)
//
#include <hip/hip_runtime.h>

// Fused Stream_PreNet: conv1 (1x7, 8->96) + conv2 (7x1, 96->96), symmetric pad,
// bf16 MFMA (16x16x32), swapped operands -> D[channel][pixel].
//  - conv1: channel-tile per wave, packed b64 o1 writes, g==3 OOB guard
//  - conv2: w2a[21] loaded EARLY (latency hides under staging+conv1) and pinned
//    in VGPRs via opaque asm (defeat remat; R2's VGPR=64 bug)
//  - __launch_bounds__(384,3): cap VGPR ~168 so 2 blocks/CU stay resident
//    (R4's (384,2) let regalloc kill occupancy -> 215us)
//  - bias1 folded into bias2e (exact under symmetric pad); float4 epilogue
// d_ws: w1t (96*64 bf16) + w2t (96*672 bf16) + bias2e (96 f32) = 141,696 B.

#define B_   8
#define H_   512
#define W_   256
#define CIN  8
#define COUT 96
#define TH   8            // output rows per block
#define TW   16           // output cols per block
#define ROWS (TH + 6)     // 14 out1 rows (halo for 7x1)
#define XC   (TW + 6)     // 22 x cols (halo for 1x7)
#define PADC 104          // o1 pixel stride (u16): 208 B, 16B-aligned, 2-way banks (floor)
#define NTHREADS 384      // 6 waves; wave w owns channels [16w, 16w+16)

typedef __bf16 bf16x8 __attribute__((ext_vector_type(8)));
typedef float  f32x4  __attribute__((ext_vector_type(4)));
typedef int    i32x4  __attribute__((ext_vector_type(4)));

__device__ __forceinline__ unsigned short f2bf(float f) {
  unsigned u = __builtin_bit_cast(unsigned, f);
  u += 0x7FFFu + ((u >> 16) & 1u);   // RNE
  return (unsigned short)(u >> 16);
}

__device__ __forceinline__ bf16x8 ld16s(const unsigned short* p) {
  i32x4 t = *(const i32x4*)p;        // 16B load -> ds_read_b128 / dwordx4
  return __builtin_bit_cast(bf16x8, t);
}

__device__ __forceinline__ f32x4 mfma16(bf16x8 a, bf16x8 b, f32x4 c) {
  return __builtin_amdgcn_mfma_f32_16x16x32_bf16(a, b, c, 0, 0, 0);
}

// jnp.pad mode='symmetric': -1->0, -2->1 ; N->N-1, N+1->N-2
__device__ __forceinline__ int symH(int i) { return i < 0 ? -1 - i : (i >= H_ ? 2 * H_ - 1 - i : i); }
__device__ __forceinline__ int symW(int i) { return i < 0 ? -1 - i : (i >= W_ ? 2 * W_ - 1 - i : i); }

// ---- weight prep ----
// w1t[ch][kc8], kc8 = tap*8+c (pad 56..63 = 0).  w2t[ch][kc], kc = tap*96+c.
// bias2e[n] = b2[n] + sum_{tap,c} W2[tap][c][n] * b1[c]   (bias1 fold, exact)
__global__ void prep_kernel(const float* __restrict__ W1, const float* __restrict__ b1,
                            const float* __restrict__ W2, const float* __restrict__ b2,
                            unsigned short* __restrict__ w1t, unsigned short* __restrict__ w2t,
                            float* __restrict__ bias2e) {
  int i = blockIdx.x * 256 + threadIdx.x;
  if (i < 96 * 64) {
    int n = i >> 6, kc = i & 63;
    float v = (kc < 56) ? W1[kc * 96 + n] : 0.f;   // W1 flat [(tap*8+c)*96 + n]
    w1t[i] = f2bf(v);
  }
  if (i < 96 * 672) {
    int n = i / 672, kc = i - n * 672;
    w2t[i] = f2bf(W2[kc * 96 + n]);                // W2 flat [(tap*96+c)*96 + n]
  }
  if (blockIdx.x == 0 && threadIdx.x < 96) {
    int n = threadIdx.x;
    float s = b2[n];
#pragma unroll 8
    for (int kc = 0; kc < 672; ++kc) {
      int c = kc - (kc / 96) * 96;
      s += W2[kc * 96 + n] * b1[c];
    }
    bias2e[n] = s;
  }
}

__global__ __launch_bounds__(NTHREADS, 3)
void conv_main(const float* __restrict__ x, const unsigned short* __restrict__ w1t,
               const unsigned short* __restrict__ w2t, const float* __restrict__ bias2e,
               float* __restrict__ out) {
  __shared__ __align__(16) unsigned short o1[ROWS][TW][PADC];  // 46,592 B
  __shared__ __align__(16) unsigned short xt[ROWS][XC][CIN];   //  4,928 B

  const int tid = threadIdx.x;
  const int w0  = blockIdx.x * TW;
  const int h0  = blockIdx.y * TH;
  const int b   = blockIdx.z;

  const int wid  = tid >> 6;        // wave id = channel tile
  const int lane = tid & 63;
  const int l15  = lane & 15;       // A: ch-in-tile / B,D: pixel
  const int g    = lane >> 4;       // k-group; D rows 4g..4g+3
  const int cf   = wid * 16 + l15;  // this wave's A channel row

  // ---- issue conv2 weight loads FIRST: latency hides under staging+conv1 ----
  bf16x8 w2a[21];
#pragma unroll
  for (int sb = 0; sb < 21; ++sb)
    w2a[sb] = ld16s(&w2t[cf * 672 + 32 * sb + 8 * g]);
#pragma unroll
  for (int sb = 0; sb < 21; ++sb) {
    i32x4 t = __builtin_bit_cast(i32x4, w2a[sb]);
    asm volatile("" : "+v"(t));      // opaque: cannot be rematerialized/spilled-cheaply
    w2a[sb] = __builtin_bit_cast(bf16x8, t);
  }

  // conv1 A-frags (weights): A[m=ch][k=tap*8+c]
  bf16x8 w1a0 = ld16s(&w1t[cf * 64 + 8 * g]);        // taps 0..3
  bf16x8 w1a1 = ld16s(&w1t[cf * 64 + 32 + 8 * g]);   // taps 4..6 (+zero tap7)
  const i32x4 z4 = {0, 0, 0, 0};

  // ---- stage x halo tile (symmetric pad applied), fp32 -> bf16 ----
  const float* xb = x + (size_t)b * H_ * W_ * CIN;
  for (int idx = tid; idx < ROWS * XC; idx += NTHREADS) {
    int rr = idx / XC, cc = idx - rr * XC;
    int hr = symH(h0 - 3 + rr);
    int wc = symW(w0 - 3 + cc);
    const float4* px = (const float4*)(xb + ((size_t)hr * W_ + wc) * CIN);
    float4 v0 = px[0], v1 = px[1];
    unsigned p0 = ((unsigned)f2bf(v0.y) << 16) | f2bf(v0.x);
    unsigned p1 = ((unsigned)f2bf(v0.w) << 16) | f2bf(v0.z);
    unsigned p2 = ((unsigned)f2bf(v1.y) << 16) | f2bf(v1.x);
    unsigned p3 = ((unsigned)f2bf(v1.w) << 16) | f2bf(v1.z);
    *(i32x4*)&xt[rr][cc][0] = (i32x4){(int)p0, (int)p1, (int)p2, (int)p3};
  }

  __syncthreads();

  // ---- conv1: each wave does all 14 rows for its 16 channels ----
#pragma unroll
  for (int rr = 0; rr < ROWS; ++rr) {
    // B[k=tap*8+c][n=pixel] = xt[rr][pixel + tap][c]
    // g==3 -> tap 7: weight rows are zero but xt[rr][l15+7] can be OOB -> zero the load.
    bf16x8 xb0 = ld16s(&xt[rr][l15 + g][0]);
    bf16x8 xb1 = (g < 3) ? ld16s(&xt[rr][l15 + 4 + g][0]) : __builtin_bit_cast(bf16x8, z4);
    f32x4 a = {0.f, 0.f, 0.f, 0.f};
    a = mfma16(w1a0, xb0, a);
    a = mfma16(w1a1, xb1, a);
    // D[m=ch 4g+r][n=pix l15] -> 4 consecutive channels, packed b64 write
    unsigned lo = ((unsigned)f2bf(a[1]) << 16) | f2bf(a[0]);
    unsigned hi = ((unsigned)f2bf(a[3]) << 16) | f2bf(a[2]);
    *(uint2*)&o1[rr][l15][wid * 16 + 4 * g] = make_uint2(lo, hi);
  }

  __syncthreads();

  // ---- conv2: B[k=c][n=pixel] from o1; 3 reads/row feed up to 21 MFMAs ----
  f32x4 acc[TH];
#pragma unroll
  for (int m = 0; m < TH; ++m) acc[m] = (f32x4){0.f, 0.f, 0.f, 0.f};

#pragma unroll
  for (int rr = 0; rr < ROWS; ++rr) {
    bf16x8 p0 = ld16s(&o1[rr][l15][8 * g]);
    bf16x8 p1 = ld16s(&o1[rr][l15][32 + 8 * g]);
    bf16x8 p2 = ld16s(&o1[rr][l15][64 + 8 * g]);
#pragma unroll
    for (int k = 0; k < 7; ++k) {
      int m = rr - k;                 // output row; folds to constants
      if (m < 0 || m >= TH) continue;
      acc[m] = mfma16(w2a[3 * k + 0], p0, acc[m]);
      acc[m] = mfma16(w2a[3 * k + 1], p1, acc[m]);
      acc[m] = mfma16(w2a[3 * k + 2], p2, acc[m]);
    }
  }

  // ---- epilogue: lane holds 4 consecutive channels at pixel l15 -> float4 ----
  const float4 bia = *(const float4*)&bias2e[wid * 16 + 4 * g];
  const size_t obase = (((size_t)b * H_ + h0) * W_ + (w0 + l15)) * COUT + wid * 16 + 4 * g;
#pragma unroll
  for (int m = 0; m < TH; ++m) {
    f32x4 v = acc[m];
    v[0] += bia.x; v[1] += bia.y; v[2] += bia.z; v[3] += bia.w;
    *(f32x4*)(out + obase + (size_t)m * (W_ * COUT)) = v;
  }
}

extern "C" void kernel_launch(void* const* d_in, const int* in_sizes, int n_in,
                              void* d_out, int out_size, void* d_ws, size_t ws_size,
                              hipStream_t stream) {
  const float* x  = (const float*)d_in[0];
  const float* W1 = (const float*)d_in[1];
  const float* b1 = (const float*)d_in[2];
  const float* W2 = (const float*)d_in[3];
  const float* b2 = (const float*)d_in[4];
  // d_in[5] = training (unused)

  unsigned short* w1t = (unsigned short*)d_ws;       // 96*64 u16
  unsigned short* w2t = w1t + 96 * 64;               // 96*672 u16
  float* bias2e = (float*)(w2t + 96 * 672);          // 96 f32
  float* out = (float*)d_out;

  prep_kernel<<<dim3(252), dim3(256), 0, stream>>>(W1, b1, W2, b2, w1t, w2t, bias2e);
  conv_main<<<dim3(W_ / TW, H_ / TH, B_), dim3(NTHREADS), 0, stream>>>(
      x, w1t, w2t, bias2e, out);
}

// Round 6
// 190.699 us; speedup vs baseline: 1.1769x; 1.1769x over previous
//
#include <hip/hip_runtime.h>

// Fused Stream_PreNet: conv1 (1x7, 8->96) + conv2 (7x1, 96->96), symmetric pad,
// bf16 MFMA (16x16x32), swapped operands -> D[channel][pixel].
// R6 design: 3-resident-block occupancy build.
//  - o1 in SLOT-MAJOR layout [rr][ch/8][pix][8ch]: conv2 ds_read_b128 is
//    conflict-free with NO padding -> LDS 47.9KB -> 3 blocks/CU.
//  - conv2 split into 3 c-slice passes (7 weight frags live, 28 VGPR;
//    pass loop NOT unrolled so loads aren't hoisted) -> VGPR fits 102 cap.
//  - __launch_bounds__(384,5): VGPR cap ~102 = the 3-block condition.
//  - NO asm pin (R4/R5 regression), bias1 folded, float4 NT epilogue stores.
// d_ws: w1t (96*64 bf16) + w2t (96*672 bf16) + bias2e (96 f32) = 141,696 B.

#define B_   8
#define H_   512
#define W_   256
#define CIN  8
#define COUT 96
#define TH   8            // output rows per block
#define TW   16           // output cols per block
#define ROWS (TH + 6)     // 14 out1 rows (halo for 7x1)
#define XC   (TW + 6)     // 22 x cols (halo for 1x7)
#define NTHREADS 384      // 6 waves; wave w owns channels [16w, 16w+16)

typedef __bf16 bf16x8 __attribute__((ext_vector_type(8)));
typedef float  f32x4  __attribute__((ext_vector_type(4)));
typedef int    i32x4  __attribute__((ext_vector_type(4)));

__device__ __forceinline__ unsigned short f2bf(float f) {
  unsigned u = __builtin_bit_cast(unsigned, f);
  u += 0x7FFFu + ((u >> 16) & 1u);   // RNE
  return (unsigned short)(u >> 16);
}

__device__ __forceinline__ bf16x8 ld16s(const unsigned short* p) {
  i32x4 t = *(const i32x4*)p;        // 16B load -> ds_read_b128 / dwordx4
  return __builtin_bit_cast(bf16x8, t);
}

__device__ __forceinline__ f32x4 mfma16(bf16x8 a, bf16x8 b, f32x4 c) {
  return __builtin_amdgcn_mfma_f32_16x16x32_bf16(a, b, c, 0, 0, 0);
}

// jnp.pad mode='symmetric': -1->0, -2->1 ; N->N-1, N+1->N-2
__device__ __forceinline__ int symH(int i) { return i < 0 ? -1 - i : (i >= H_ ? 2 * H_ - 1 - i : i); }
__device__ __forceinline__ int symW(int i) { return i < 0 ? -1 - i : (i >= W_ ? 2 * W_ - 1 - i : i); }

// ---- weight prep ----
// w1t[ch][kc8], kc8 = tap*8+c (pad 56..63 = 0).  w2t[ch][kc], kc = tap*96+c.
// bias2e[n] = b2[n] + sum_{tap,c} W2[tap][c][n] * b1[c]   (bias1 fold, exact)
__global__ void prep_kernel(const float* __restrict__ W1, const float* __restrict__ b1,
                            const float* __restrict__ W2, const float* __restrict__ b2,
                            unsigned short* __restrict__ w1t, unsigned short* __restrict__ w2t,
                            float* __restrict__ bias2e) {
  int i = blockIdx.x * 256 + threadIdx.x;
  if (i < 96 * 64) {
    int n = i >> 6, kc = i & 63;
    float v = (kc < 56) ? W1[kc * 96 + n] : 0.f;   // W1 flat [(tap*8+c)*96 + n]
    w1t[i] = f2bf(v);
  }
  if (i < 96 * 672) {
    int n = i / 672, kc = i - n * 672;
    w2t[i] = f2bf(W2[kc * 96 + n]);                // W2 flat [(tap*96+c)*96 + n]
  }
  if (blockIdx.x == 0 && threadIdx.x < 96) {
    int n = threadIdx.x;
    float s = b2[n];
#pragma unroll 8
    for (int kc = 0; kc < 672; ++kc) {
      int c = kc - (kc / 96) * 96;
      s += W2[kc * 96 + n] * b1[c];
    }
    bias2e[n] = s;
  }
}

__global__ __launch_bounds__(NTHREADS, 5)   // VGPR cap ~102 -> 3 blocks/CU
void conv_main(const float* __restrict__ x, const unsigned short* __restrict__ w1t,
               const unsigned short* __restrict__ w2t, const float* __restrict__ bias2e,
               float* __restrict__ out) {
  // o1 slot-major: [row][slot=ch/8][pixel][8 ch] -> conv2 reads are 16
  // consecutive 16B chunks per quarter-wave: conflict-free, no padding.
  __shared__ __align__(16) unsigned short o1[ROWS][12][TW][8];  // 43,008 B
  __shared__ __align__(16) unsigned short xt[ROWS][XC][CIN];    //  4,928 B

  const int tid = threadIdx.x;
  const int w0  = blockIdx.x * TW;
  const int h0  = blockIdx.y * TH;
  const int b   = blockIdx.z;

  const int wid  = tid >> 6;        // wave id = channel tile
  const int lane = tid & 63;
  const int l15  = lane & 15;       // A: ch-in-tile / B,D: pixel
  const int g    = lane >> 4;       // k-group; D rows 4g..4g+3
  const int cf   = wid * 16 + l15;  // this wave's A channel row

  // ---- stage x halo tile (symmetric pad applied), fp32 -> bf16 ----
  const float* xb = x + (size_t)b * H_ * W_ * CIN;
  if (tid < ROWS * XC) {
    int rr = tid / XC, cc = tid - rr * XC;
    int hr = symH(h0 - 3 + rr);
    int wc = symW(w0 - 3 + cc);
    const float4* px = (const float4*)(xb + ((size_t)hr * W_ + wc) * CIN);
    float4 v0 = px[0], v1 = px[1];
    unsigned p0 = ((unsigned)f2bf(v0.y) << 16) | f2bf(v0.x);
    unsigned p1 = ((unsigned)f2bf(v0.w) << 16) | f2bf(v0.z);
    unsigned p2 = ((unsigned)f2bf(v1.y) << 16) | f2bf(v1.x);
    unsigned p3 = ((unsigned)f2bf(v1.w) << 16) | f2bf(v1.z);
    *(i32x4*)&xt[rr][cc][0] = (i32x4){(int)p0, (int)p1, (int)p2, (int)p3};
  }

  // conv1 A-frags (weights): A[m=ch][k=tap*8+c]
  bf16x8 w1a0 = ld16s(&w1t[cf * 64 + 8 * g]);        // taps 0..3
  bf16x8 w1a1 = ld16s(&w1t[cf * 64 + 32 + 8 * g]);   // taps 4..6 (+zero tap7)
  const i32x4 z4 = {0, 0, 0, 0};

  __syncthreads();

  // ---- conv1: each wave does all 14 rows for its 16 channels ----
#pragma unroll
  for (int rr = 0; rr < ROWS; ++rr) {
    // B[k=tap*8+c][n=pixel] = xt[rr][pixel + tap][c]
    // g==3 -> tap 7: weight rows are zero but xt[rr][l15+7] can be OOB -> zero the load.
    bf16x8 xb0 = ld16s(&xt[rr][l15 + g][0]);
    bf16x8 xb1 = (g < 3) ? ld16s(&xt[rr][l15 + 4 + g][0]) : __builtin_bit_cast(bf16x8, z4);
    f32x4 a = {0.f, 0.f, 0.f, 0.f};
    a = mfma16(w1a0, xb0, a);
    a = mfma16(w1a1, xb1, a);
    // D[m=ch 4g+r][n=pix l15]: abs ch = wid*16+4g+r -> slot 2wid+(g>>1), half (g&1)
    unsigned lo = ((unsigned)f2bf(a[1]) << 16) | f2bf(a[0]);
    unsigned hi = ((unsigned)f2bf(a[3]) << 16) | f2bf(a[2]);
    *(uint2*)&o1[rr][2 * wid + (g >> 1)][l15][(g & 1) * 4] = make_uint2(lo, hi);
  }

  __syncthreads();

  // ---- conv2 in 3 c-slice passes: pass j covers channels-in 32j..32j+31 ----
  f32x4 acc[TH];
#pragma unroll
  for (int m = 0; m < TH; ++m) acc[m] = (f32x4){0.f, 0.f, 0.f, 0.f};

#pragma unroll 1                      // do NOT hoist all 21 weight frags
  for (int j = 0; j < 3; ++j) {
    bf16x8 w2f[7];
#pragma unroll
    for (int k = 0; k < 7; ++k)       // A[m=cf][kk=8g+jj] = W2[cf][tap k, c=32j+8g+jj]
      w2f[k] = ld16s(&w2t[cf * 672 + k * 96 + 32 * j + 8 * g]);
#pragma unroll
    for (int rr = 0; rr < ROWS; ++rr) {
      bf16x8 p = ld16s(&o1[rr][4 * j + g][l15][0]);   // B[k=c][n=pix]
#pragma unroll
      for (int k = 0; k < 7; ++k) {
        int m = rr - k;               // output row; folds to constants
        if (m < 0 || m >= TH) continue;
        acc[m] = mfma16(w2f[k], p, acc[m]);
      }
    }
  }

  // ---- epilogue: lane holds 4 consecutive channels at pixel l15 -> NT float4 ----
  const float4 bia = *(const float4*)&bias2e[wid * 16 + 4 * g];
  const size_t obase = (((size_t)b * H_ + h0) * W_ + (w0 + l15)) * COUT + wid * 16 + 4 * g;
#pragma unroll
  for (int m = 0; m < TH; ++m) {
    f32x4 v = acc[m];
    v[0] += bia.x; v[1] += bia.y; v[2] += bia.z; v[3] += bia.w;
    __builtin_nontemporal_store(v, (f32x4*)(out + obase + (size_t)m * (W_ * COUT)));
  }
}

extern "C" void kernel_launch(void* const* d_in, const int* in_sizes, int n_in,
                              void* d_out, int out_size, void* d_ws, size_t ws_size,
                              hipStream_t stream) {
  const float* x  = (const float*)d_in[0];
  const float* W1 = (const float*)d_in[1];
  const float* b1 = (const float*)d_in[2];
  const float* W2 = (const float*)d_in[3];
  const float* b2 = (const float*)d_in[4];
  // d_in[5] = training (unused)

  unsigned short* w1t = (unsigned short*)d_ws;       // 96*64 u16
  unsigned short* w2t = w1t + 96 * 64;               // 96*672 u16
  float* bias2e = (float*)(w2t + 96 * 672);          // 96 f32
  float* out = (float*)d_out;

  prep_kernel<<<dim3(252), dim3(256), 0, stream>>>(W1, b1, W2, b2, w1t, w2t, bias2e);
  conv_main<<<dim3(W_ / TW, H_ / TH, B_), dim3(NTHREADS), 0, stream>>>(
      x, w1t, w2t, bias2e, out);
}